// Round 8
// baseline (282.013 us; speedup 1.0000x reference)
//
#include <hip/hip_runtime.h>

// DEChannelPool: 6 soft-morphology branches + per-channel BN + 1x1 conv + BN + ReLU.
// Trick 1: exp(beta*(w±x)) = exp(beta*w)*exp(±beta*x): 2 exps per input pixel.
// Trick 2: BN+conv fold to alpha*log2(S) + const; const cancels in final scalar BN.
// R6: merged-side stencils, slab partials (no pixel atomics), s_load weights. 280 us.
// R7: cooperative fusion was NEUTRAL (grid.sync cost ate the launch-gap savings) and
//     ambiguous under rocprof -> reverted.
// R8: attack the LDS issue bound (k_stats = 371 LDS-pipe instrs/wave ~ 95 us).
//     (a) k_stats: 2-adjacent-cols/thread on 64x64 tiles, float2/b64 LDS ops
//         (per-pixel LDS instrs ~1.8x down; 40.3 KB LDS -> 3 blocks/CU, fine since
//         issue-bound not latency-bound); (b) k_reduce: stride 40 + float2 plane
//         writes; (c) ws zeroing folded into k_wexp (memset stream-op removed).

#define BETA 15.0f
#define MSHIFT 25.0f
#define INV_BETA (1.0f/15.0f)
#define LN2 0.6931471805599453f
#define EPSB 1e-5f
#define Hn 192
#define Wn 192
#define HWn (192*192)
#define N1 (8*192*192)
#define SFLOOR 1e-37f

// ---- stats geometry: 64r x 64c tile, 8-row strips x 2-col threads, 256 thr ----
#define STDH 70             // 64 + 2*3
#define STDW 70
#define STSTR 72            // even stride: b64-aligned pairs; 8*72%32==0 -> 2-way strips
#define SNPAIR (STDH*35)    // 2450 col-pairs

// ---- reduce geometry: 32r x 32c tile, 4-row strips, 256 thr, BOTH sides ----
#define RDH 38
#define RSTR 40             // even stride for float2 writes; 4*40%32==0 -> 2-way strips
#define RNPAIR (RDH*19)     // 722 col-pairs
#define RPITER 3

// workspace layout (float offsets)
#define WS_SUM   0
#define WS_SQS   384
#define WS_SCAL  768
#define WS_WG    772
#define WS_YE    (772 + 3456)
#define WS_YD    (WS_YE + 294912)
#define WS_SLAB  (WS_YE + 2*294912)   // [2 sides * NS grps][8 b][HWn]

// also zeros sum/sqs/scal (first 772 floats of ws) -- replaces hipMemsetAsync
__global__ void k_wexp(const float* __restrict__ we,
                       const float* __restrict__ wd,
                       float* __restrict__ ws) {
    int idx = blockIdx.x * 256 + threadIdx.x;
    if (idx < 772) ws[idx] = 0.f;
    if (idx >= 3456) return;
    int kb = idx / 576;            // 0..5 = side*3+br (0-2 erosion, 3-5 dilation)
    int rem = idx - kb * 576;      // c*9 + tap
    float w = (kb < 3) ? we[kb * 576 + rem] : wd[(kb - 3) * 576 + rem];
    ws[WS_WG + idx] = __expf(BETA * w);
}

// ---- single-column register-rotating stencil (reduce kernel) ----
template<int D, int H, int STR>
__device__ __forceinline__ void sweepT(const float* __restrict__ P,
                                       int py0, int px,
                                       const float* __restrict__ wgp,
                                       float* __restrict__ S) {
    float W[9];
#pragma unroll
    for (int k2 = 0; k2 < 9; ++k2) W[k2] = wgp[k2];
#pragma unroll
    for (int k = 0; k < H; ++k) S[k] = 0.f;
    const float* base = P + (py0 - D + 3) * STR + (px - D);
#pragma unroll
    for (int r = 0; r < H + 2 * D; ++r) {
        float va = base[r * STR];
        float vb = base[r * STR + D];
        float vc = base[r * STR + 2 * D];
#pragma unroll
        for (int i = 0; i < 3; ++i) {
            int k = r - i * D;
            if (k >= 0 && k < H) {
                S[k] = fmaf(W[i*3+0], va, S[k]);
                S[k] = fmaf(W[i*3+1], vb, S[k]);
                S[k] = fmaf(W[i*3+2], vc, S[k]);
            }
        }
    }
}

// ---- 2-column register-rotating stencil (stats kernel), b64 plane reads ----
// Thread owns output cols {2t, 2t+1} (plane dword cols {2t+3, 2t+4}), 8 rows.
template<int D>
__device__ __forceinline__ void sweep2(const float* __restrict__ P,
                                       int py0, int tcol,
                                       const float* __restrict__ wgp,
                                       float* __restrict__ SA,
                                       float* __restrict__ SB) {
    float W[9];
#pragma unroll
    for (int k2 = 0; k2 < 9; ++k2) W[k2] = wgp[k2];
#pragma unroll
    for (int k = 0; k < 8; ++k) { SA[k] = 0.f; SB[k] = 0.f; }
    const int colbase = (D == 1) ? (2 * tcol + 2) : (2 * tcol);
#pragma unroll
    for (int r = 0; r < 8 + 2 * D; ++r) {
        const float2* row =
            (const float2*)(P + (py0 - D + 3 + r) * STSTR + colbase);
        float2 v0 = row[0], v1 = row[1];
        float ta0, ta1, ta2, tb0, tb1, tb2;
        if (D == 1) {
            ta0 = v0.x; ta1 = v0.y; ta2 = v1.x;
            tb0 = v0.y; tb1 = v1.x; tb2 = v1.y;
        } else {
            float2 v2 = row[2], v3 = row[3];
            if (D == 2) {
                ta0 = v0.y; ta1 = v1.y; ta2 = v2.y;   // odd taps (col A)
                tb0 = v1.x; tb1 = v2.x; tb2 = v3.x;   // even taps (col B)
            } else {
                ta0 = v0.x; ta1 = v1.y; ta2 = v3.x;
                tb0 = v0.y; tb1 = v2.x; tb2 = v3.y;
            }
        }
#pragma unroll
        for (int i = 0; i < 3; ++i) {
            int k = r - i * D;
            if (k >= 0 && k < 8) {
                SA[k] = fmaf(W[i*3+0], ta0, SA[k]);
                SA[k] = fmaf(W[i*3+1], ta1, SA[k]);
                SA[k] = fmaf(W[i*3+2], ta2, SA[k]);
                SB[k] = fmaf(W[i*3+0], tb0, SB[k]);
                SB[k] = fmaf(W[i*3+1], tb1, SB[k]);
                SB[k] = fmaf(W[i*3+2], tb2, SB[k]);
            }
        }
    }
}

__device__ __forceinline__ void red2(float a, float b2, int lane, float* rs, float* rq) {
#pragma unroll
    for (int off = 32; off; off >>= 1) {
        a  += __shfl_down(a, off, 64);
        b2 += __shfl_down(b2, off, 64);
    }
    if (lane == 0) { *rs = a; *rq = b2; }
}

// grid (9 tiles, 512 b*c), 256 threads. 64x64 tile, both sides, 16 px/thread.
__global__ __launch_bounds__(256, 3) void k_stats(
    const float* __restrict__ x, const float* __restrict__ wg,
    float* __restrict__ sum, float* __restrict__ sqs) {
    __shared__ float EX[STDH * STSTR], EY[STDH * STSTR];
    __shared__ float redS[4][6], redQ[4][6];
    const int tid = threadIdx.x;
    const int p = blockIdx.y;            // b*64 + c
    const int c = p & 63;
    const int t = blockIdx.x;
    const int h0 = (t / 3) * 64, w0 = (t % 3) * 64;

    const float* xp = x + (size_t)p * HWn;
    {   // pair loader: 2450 col-pairs, float2 writes to both planes
        int r = tid / 35, pp = tid - r * 35;
        for (int l = tid; l < SNPAIR; l += 256) {
            int gh = h0 - 3 + r;
            int gw0 = w0 - 3 + 2 * pp;
            float va = 0.f, vb = 0.f;
            if ((unsigned)gh < (unsigned)Hn) {
                if ((unsigned)gw0 < (unsigned)Wn)       va = xp[gh * Wn + gw0];
                if ((unsigned)(gw0+1) < (unsigned)Wn)   vb = xp[gh * Wn + gw0 + 1];
            }
            float ba = BETA * va, bb = BETA * vb;   // OOB -> 0 -> exp(-M), correct
            *(float2*)&EX[r * STSTR + 2 * pp] =
                make_float2(__expf(-ba - MSHIFT), __expf(-bb - MSHIFT));
            *(float2*)&EY[r * STSTR + 2 * pp] =
                make_float2(__expf( ba - MSHIFT), __expf( bb - MSHIFT));
            r += 7; pp += 11;            // 256 = 7*35 + 11
            if (pp >= 35) { pp -= 35; ++r; }
        }
    }
    __syncthreads();

    const int tcol = tid & 31;
    const int py0 = (tid >> 5) * 8;
    const int lane = tid & 63, wv = tid >> 6;
    const float LI = LN2 * INV_BETA, MI = MSHIFT * INV_BETA;

#define DO_BR_STATS(D, SLOT, PL, AL, AM) { \
    float SA[8], SB[8]; \
    sweep2<D>(PL, py0, tcol, wg + (SLOT) * 576 + c * 9, SA, SB); \
    float sv = 0.f, qv = 0.f; \
    _Pragma("unroll") \
    for (int k = 0; k < 8; ++k) { \
        float ma = fmaf(__log2f(fmaxf(SA[k], SFLOOR)), AL, AM); \
        float mb = fmaf(__log2f(fmaxf(SB[k], SFLOOR)), AL, AM); \
        sv += ma + mb; qv = fmaf(ma, ma, fmaf(mb, mb, qv)); \
    } \
    red2(sv, qv, lane, &redS[wv][SLOT], &redQ[wv][SLOT]); }

    DO_BR_STATS(1, 0, EX, -LI, -MI)
    DO_BR_STATS(2, 1, EX, -LI, -MI)
    DO_BR_STATS(3, 2, EX, -LI, -MI)
    DO_BR_STATS(1, 3, EY,  LI,  MI)
    DO_BR_STATS(2, 4, EY,  LI,  MI)
    DO_BR_STATS(3, 5, EY,  LI,  MI)
#undef DO_BR_STATS

    __syncthreads();
    if (tid < 6)
        atomicAdd(&sum[tid * 64 + c],
                  redS[0][tid] + redS[1][tid] + redS[2][tid] + redS[3][tid]);
    else if (tid < 12) {
        int v = tid - 6;
        atomicAdd(&sqs[v * 64 + c],
                  redQ[0][v] + redQ[1][v] + redQ[2][v] + redQ[3][v]);
    }
}

// ---- alpha into LDS: slot = side*192 + br*64 + c ----
__device__ __forceinline__ void alpha_fill(
    const float* __restrict__ sum, const float* __restrict__ sqs,
    const float* __restrict__ bn_ge, const float* __restrict__ bn_gd,
    const float* __restrict__ conve, const float* __restrict__ convd,
    float* __restrict__ al, int tid) {
    for (int l = tid; l < 384; l += 256) {
        int side_ = l / 192, ch = l - side_ * 192;
        float mean = sum[l] * (1.0f / N1);
        float var  = sqs[l] * (1.0f / N1) - mean * mean;
        float inv  = rsqrtf(fmaxf(var, 0.f) + EPSB);
        float g  = side_ ? bn_gd[ch] : bn_ge[ch];
        float cw = side_ ? convd[ch] : conve[ch];
        float sgn = side_ ? 1.f : -1.f;
        al[l] = sgn * cw * g * inv * INV_BETA * LN2;
    }
}

// grid (36 tiles, 8 b, NS grps), 256 threads. 32x32 tile, NC channels, both sides.
template<int NS>
__global__ __launch_bounds__(256, 4) void k_reduce(
    const float* __restrict__ x, const float* __restrict__ wg,
    const float* __restrict__ sum, const float* __restrict__ sqs,
    const float* __restrict__ bn_ge, const float* __restrict__ bn_gd,
    const float* __restrict__ conve, const float* __restrict__ convd,
    float* __restrict__ ye, float* __restrict__ yd,
    float* __restrict__ slab, float* __restrict__ scal) {
    constexpr int NC = 64 / NS;
    __shared__ float EX[RDH * RSTR], EY[RDH * RSTR];
    __shared__ float al[384];
    __shared__ float redA[4][4];
    const int tid = threadIdx.x;
    const int t = blockIdx.x;
    const int b = blockIdx.y;
    const int grp = blockIdx.z;
    const int c0 = grp * NC;
    const int tr = t / 6, tc = t - tr * 6;
    const int h0 = tr * 32, w0 = tc * 32;
    const int px = (tid & 31) + 3;
    const int py0 = (tid >> 5) * 4;
    const float* xb = x + (size_t)b * 64 * HWn;

    alpha_fill(sum, sqs, bn_ge, bn_gd, conve, convd, al, tid);

    float accE[4] = {0.f, 0.f, 0.f, 0.f}, accD[4] = {0.f, 0.f, 0.f, 0.f};
    float2 L[RPITER];

    // prologue: prefetch channel c0 (raw x pairs) into registers
    {
        const float* xp = xb + (size_t)c0 * HWn;
        int r = tid / 19, pp = tid - r * 19;
#pragma unroll
        for (int i = 0; i < RPITER; ++i) {
            int l = tid + i * 256;
            float va = 0.f, vb = 0.f;
            if (l < RNPAIR) {
                int gh = h0 - 3 + r, gw0 = w0 - 3 + 2 * pp;
                if ((unsigned)gh < (unsigned)Hn) {
                    if ((unsigned)gw0 < (unsigned)Wn)     va = xp[gh * Wn + gw0];
                    if ((unsigned)(gw0+1) < (unsigned)Wn) vb = xp[gh * Wn + gw0 + 1];
                }
            }
            L[i] = make_float2(va, vb);
            r += 13; pp += 9;            // 256 = 13*19 + 9
            if (pp >= 19) { pp -= 19; ++r; }
        }
    }

    for (int ci = 0; ci < NC; ++ci) {
        __syncthreads();                  // planes free (iter 0: al visible)
        {   // write phase: float2 stores to both planes
            int r = tid / 19, pp = tid - r * 19;
#pragma unroll
            for (int i = 0; i < RPITER; ++i) {
                int l = tid + i * 256;
                if (l < RNPAIR) {
                    float ba = BETA * L[i].x, bb = BETA * L[i].y;
                    *(float2*)&EX[r * RSTR + 2 * pp] =
                        make_float2(__expf(-ba - MSHIFT), __expf(-bb - MSHIFT));
                    *(float2*)&EY[r * RSTR + 2 * pp] =
                        make_float2(__expf( ba - MSHIFT), __expf( bb - MSHIFT));
                }
                r += 13; pp += 9;
                if (pp >= 19) { pp -= 19; ++r; }
            }
        }
        __syncthreads();
        if (ci < NC - 1) {                // prefetch next channel (overlaps sweeps)
            const float* xp = xb + (size_t)(c0 + ci + 1) * HWn;
            int r = tid / 19, pp = tid - r * 19;
#pragma unroll
            for (int i = 0; i < RPITER; ++i) {
                int l = tid + i * 256;
                float va = 0.f, vb = 0.f;
                if (l < RNPAIR) {
                    int gh = h0 - 3 + r, gw0 = w0 - 3 + 2 * pp;
                    if ((unsigned)gh < (unsigned)Hn) {
                        if ((unsigned)gw0 < (unsigned)Wn)     va = xp[gh * Wn + gw0];
                        if ((unsigned)(gw0+1) < (unsigned)Wn) vb = xp[gh * Wn + gw0 + 1];
                    }
                }
                L[i] = make_float2(va, vb);
                r += 13; pp += 9;
                if (pp >= 19) { pp -= 19; ++r; }
            }
        }
        const int c = c0 + ci;
#define DO_BR_ACC(D, SIDE, BR, PL, ACC) { \
        float S[4]; \
        sweepT<D, 4, RSTR>(PL, py0, px, wg + ((SIDE) * 3 + (BR)) * 576 + c * 9, S); \
        const float a_ = al[(SIDE) * 192 + (BR) * 64 + c]; \
        _Pragma("unroll") \
        for (int k = 0; k < 4; ++k) \
            ACC[k] = fmaf(a_, __log2f(fmaxf(S[k], SFLOOR)), ACC[k]); }

        DO_BR_ACC(1, 0, 0, EX, accE)
        DO_BR_ACC(2, 0, 1, EX, accE)
        DO_BR_ACC(3, 0, 2, EX, accE)
        DO_BR_ACC(1, 1, 0, EY, accD)
        DO_BR_ACC(2, 1, 1, EY, accD)
        DO_BR_ACC(3, 1, 2, EY, accD)
#undef DO_BR_ACC
    }

    if constexpr (NS == 1) {
        const int oidx = b * HWn + (h0 + py0) * Wn + (w0 + px - 3);
#pragma unroll
        for (int k = 0; k < 4; ++k) {
            ye[oidx + k * Wn] = accE[k];
            yd[oidx + k * Wn] = accD[k];
        }
        float se = 0.f, qe = 0.f, sd = 0.f, qd = 0.f;
#pragma unroll
        for (int k = 0; k < 4; ++k) {
            se += accE[k]; qe = fmaf(accE[k], accE[k], qe);
            sd += accD[k]; qd = fmaf(accD[k], accD[k], qd);
        }
        const int lane = tid & 63, wv = tid >> 6;
        float v4[4] = {se, qe, sd, qd};
#pragma unroll
        for (int j = 0; j < 4; ++j) {
            float tv = v4[j];
#pragma unroll
            for (int off = 32; off; off >>= 1) tv += __shfl_down(tv, off, 64);
            if (lane == 0) redA[wv][j] = tv;
        }
        __syncthreads();
        if (tid < 4)
            atomicAdd(&scal[tid],
                      redA[0][tid] + redA[1][tid] + redA[2][tid] + redA[3][tid]);
    } else {
        float* pe = slab + ((size_t)grp * 8 + b) * HWn;
        float* pd = slab + ((size_t)(NS + grp) * 8 + b) * HWn;
        const int oidx = (h0 + py0) * Wn + (w0 + px - 3);
#pragma unroll
        for (int k = 0; k < 4; ++k) {
            pe[oidx + k * Wn] = accE[k];
            pd[oidx + k * Wn] = accD[k];
        }
    }
}

// NS>1 path: sum the NS chunk partials per pixel -> ye/yd + scalar BN stats.
template<int NS>
__global__ __launch_bounds__(256) void k_fsum(
    const float* __restrict__ slab,
    float* __restrict__ ye, float* __restrict__ yd, float* __restrict__ scal) {
    int i = blockIdx.x * 256 + threadIdx.x;   // < 294912
    int b = i / HWn, rem = i - b * HWn;
    float e = 0.f, d = 0.f;
#pragma unroll
    for (int g = 0; g < NS; ++g) {
        e += slab[((size_t)g * 8 + b) * HWn + rem];
        d += slab[((size_t)(NS + g) * 8 + b) * HWn + rem];
    }
    ye[i] = e; yd[i] = d;
    float v[4] = {e, e * e, d, d * d};
    __shared__ float red[4][4];
    int lane = threadIdx.x & 63, wv = threadIdx.x >> 6;
#pragma unroll
    for (int k = 0; k < 4; ++k) {
        float tv = v[k];
#pragma unroll
        for (int off = 32; off; off >>= 1) tv += __shfl_down(tv, off, 64);
        if (lane == 0) red[wv][k] = tv;
    }
    __syncthreads();
    if (threadIdx.x < 4)
        atomicAdd(&scal[threadIdx.x],
                  red[0][threadIdx.x] + red[1][threadIdx.x] + red[2][threadIdx.x] + red[3][threadIdx.x]);
}

__global__ __launch_bounds__(256) void k_final(
    const float* __restrict__ ye, const float* __restrict__ yd,
    const float* __restrict__ scal,
    const float* __restrict__ g_e, const float* __restrict__ b_e,
    const float* __restrict__ g_d, const float* __restrict__ b_d,
    float* __restrict__ out) {
    int i = blockIdx.x * 256 + threadIdx.x;  // < 294912
    float me_ = scal[0] * (1.0f / N1);
    float ve  = scal[1] * (1.0f / N1) - me_ * me_;
    float ie  = rsqrtf(fmaxf(ve, 0.f) + EPSB);
    float md_ = scal[2] * (1.0f / N1);
    float vd  = scal[3] * (1.0f / N1) - md_ * md_;
    float idv = rsqrtf(fmaxf(vd, 0.f) + EPSB);
    float ge = g_e[0], be = b_e[0];
    float gd = g_d[0], bd = b_d[0];
    int b = i / HWn, rem = i - b * HWn;
    float oe = fmaxf(ge * (ye[i] - me_) * ie + be, 0.f);
    float od = fmaxf(gd * (yd[i] - md_) * idv + bd, 0.f);
    out[(size_t)(b * 2) * HWn + rem]     = oe;
    out[(size_t)(b * 2 + 1) * HWn + rem] = od;
}

extern "C" void kernel_launch(void* const* d_in, const int* in_sizes, int n_in,
                              void* d_out, int out_size, void* d_ws, size_t ws_size,
                              hipStream_t stream) {
    const float* x     = (const float*)d_in[0];
    const float* we    = (const float*)d_in[1];
    const float* wd    = (const float*)d_in[2];
    const float* bn_ge = (const float*)d_in[3];
    const float* bn_gd = (const float*)d_in[5];
    const float* conve = (const float*)d_in[7];
    const float* convd = (const float*)d_in[8];
    const float* g_e   = (const float*)d_in[9];
    const float* b_e   = (const float*)d_in[10];
    const float* g_d   = (const float*)d_in[11];
    const float* b_d   = (const float*)d_in[12];
    float* ws = (float*)d_ws;

    const size_t need4 = (size_t)(WS_SLAB + 4 * 2 * 294912) * sizeof(float); // 11.8 MB
    const size_t need2 = (size_t)(WS_SLAB + 2 * 2 * 294912) * sizeof(float); //  7.1 MB
    const int ns = (ws_size >= need4) ? 4 : (ws_size >= need2) ? 2 : 1;

    hipLaunchKernelGGL(k_wexp, dim3(14), dim3(256), 0, stream, we, wd, ws);
    hipLaunchKernelGGL(k_stats, dim3(9, 512), dim3(256), 0, stream,
                       x, ws + WS_WG, ws + WS_SUM, ws + WS_SQS);
    if (ns == 4) {
        hipLaunchKernelGGL((k_reduce<4>), dim3(36, 8, 4), dim3(256), 0, stream,
                           x, ws + WS_WG, ws + WS_SUM, ws + WS_SQS, bn_ge, bn_gd,
                           conve, convd, ws + WS_YE, ws + WS_YD, ws + WS_SLAB,
                           ws + WS_SCAL);
        hipLaunchKernelGGL((k_fsum<4>), dim3(1152), dim3(256), 0, stream,
                           ws + WS_SLAB, ws + WS_YE, ws + WS_YD, ws + WS_SCAL);
    } else if (ns == 2) {
        hipLaunchKernelGGL((k_reduce<2>), dim3(36, 8, 2), dim3(256), 0, stream,
                           x, ws + WS_WG, ws + WS_SUM, ws + WS_SQS, bn_ge, bn_gd,
                           conve, convd, ws + WS_YE, ws + WS_YD, ws + WS_SLAB,
                           ws + WS_SCAL);
        hipLaunchKernelGGL((k_fsum<2>), dim3(1152), dim3(256), 0, stream,
                           ws + WS_SLAB, ws + WS_YE, ws + WS_YD, ws + WS_SCAL);
    } else {
        hipLaunchKernelGGL((k_reduce<1>), dim3(36, 8, 1), dim3(256), 0, stream,
                           x, ws + WS_WG, ws + WS_SUM, ws + WS_SQS, bn_ge, bn_gd,
                           conve, convd, ws + WS_YE, ws + WS_YD, ws, ws + WS_SCAL);
    }
    hipLaunchKernelGGL(k_final, dim3(1152), dim3(256), 0, stream,
                       ws + WS_YE, ws + WS_YD, ws + WS_SCAL, g_e, b_e, g_d, b_d,
                       (float*)d_out);
}